// Round 1
// 932.959 us; speedup vs baseline: 1.0422x; 1.0422x over previous
//
#include <hip/hip_runtime.h>
#include <hip/hip_bf16.h>
#include <stdint.h>

typedef __bf16 bf16_t;
typedef __bf16 bf16x8 __attribute__((ext_vector_type(8)));
typedef float f32x4 __attribute__((ext_vector_type(4)));

// ---------- constants ----------
#define BS       4096
#define SEQ      20
#define SEQP     22          // padded rows per batch elem (2 zero rows)
#define EMB      768
#define FEAT     512
#define KA       2304        // 3*768 virtual K
// d_out layout (floats)
#define WV_BASE   (41943040L)   // 4096*512*20
#define SENT_BASE (44040192L)

// ws layout (bytes). P offset depends on runtime chunk size CB:
//   P_OFF = XPAD_OFF + CB*22*768*2
#define BT_OFF    0L                        // 1536*2304*2 = 7077888
#define WPT_OFF   7077888L                  // 512*768*2   = 786432
#define SENTX_OFF 7864320L                  // 4096*768*2  = 6291456
#define XPAD_OFF  14155776L
#define WS_MIN    111673344L                // CB=1024 (4-chunk) total
#define WS_FULL   404226048L                // CB=4096 (unchunked) total

__device__ __forceinline__ void async_copy16(void* lds, const void* g) {
  __builtin_amdgcn_global_load_lds(
      (__attribute__((address_space(1))) void*)(void*)g,
      (__attribute__((address_space(3))) void*)lds,
      16, 0, 0);
}

// ---------- pack kernels ----------
// one chunk of words [CB,20,768] fp32 -> Xpad [CB,22,768] bf16 (rows 20,21 zero)
__global__ void pack_xpad(const float* __restrict__ words, bf16_t* __restrict__ Xpad) {
  long idx4 = ((long)blockIdx.x * blockDim.x + threadIdx.x) * 4;   // < CB*22*768
  long row = idx4 / EMB;          // b_local*22 + r
  int  d   = (int)(idx4 % EMB);
  long b   = row / SEQP;
  int  r   = (int)(row % SEQP);
  ushort4 o;
  if (r < SEQ) {
    float4 v = *(const float4*)(words + ((b * SEQ + r) * EMB + d));
    o.x = __builtin_bit_cast(unsigned short, (bf16_t)v.x);
    o.y = __builtin_bit_cast(unsigned short, (bf16_t)v.y);
    o.z = __builtin_bit_cast(unsigned short, (bf16_t)v.z);
    o.w = __builtin_bit_cast(unsigned short, (bf16_t)v.w);
  } else {
    o.x = 0; o.y = 0; o.z = 0; o.w = 0;
  }
  *(ushort4*)(&Xpad[idx4]) = o;
}

__global__ void pack_sent(const float* __restrict__ sent, bf16_t* __restrict__ Xs) {
  long idx4 = ((long)blockIdx.x * blockDim.x + threadIdx.x) * 4;   // < 4096*768
  float4 v = *(const float4*)(sent + idx4);
  ushort4 o;
  o.x = __builtin_bit_cast(unsigned short, (bf16_t)v.x);
  o.y = __builtin_bit_cast(unsigned short, (bf16_t)v.y);
  o.z = __builtin_bit_cast(unsigned short, (bf16_t)v.z);
  o.w = __builtin_bit_cast(unsigned short, (bf16_t)v.w);
  *(ushort4*)(&Xs[idx4]) = o;
}

// Bt[n][k], n in [0,1536), k in [0,2304): group g=n>>9, c=n&511, j=k/768, d=k%768
__global__ void pack_bt(const float* __restrict__ W1, const float* __restrict__ W2,
                        const float* __restrict__ W3, bf16_t* __restrict__ Bt) {
  long idx = (long)blockIdx.x * blockDim.x + threadIdx.x;          // < 1536*2304
  int n = (int)(idx / KA), k = (int)(idx % KA);
  int g = n >> 9, c = n & 511;
  int j = k / EMB, d = k % EMB;
  float v = 0.f;
  if (j <= g) {
    const float* W = (g == 0) ? W1 : ((g == 1) ? W2 : W3);
    v = W[((long)j * EMB + d) * FEAT + c];
  }
  Bt[idx] = (bf16_t)v;
}

// Wpt[n][k] = Wp[k][n]
__global__ void pack_wpt(const float* __restrict__ Wp, bf16_t* __restrict__ Wpt) {
  long idx = (long)blockIdx.x * blockDim.x + threadIdx.x;          // < 512*768
  int n = (int)(idx / EMB), k = (int)(idx % EMB);
  Wpt[idx] = (bf16_t)Wp[(long)k * FEAT + n];
}

// ---------- sentence GEMM (proven 128^2 2-barrier kernel, K=768, small) ----------
__global__ __launch_bounds__(256, 2)
void gemm_sent(const bf16_t* __restrict__ A, const bf16_t* __restrict__ Bt,
               const float* __restrict__ bias, float* __restrict__ S) {
  __shared__ bf16_t As[128 * 64];
  __shared__ bf16_t Bs[128 * 64];

  const int tid  = threadIdx.x;
  const int lane = tid & 63;
  const int w    = tid >> 6;
  const int m0   = blockIdx.x * 128;
  const int n0t  = blockIdx.y * 128;

  long agbase[4], bgbase[4];
  int  ldsoff[4];
  #pragma unroll
  for (int i = 0; i < 4; i++) {
    int r = w * 32 + i * 8 + (lane >> 3);
    int cg = (lane & 7) ^ (r & 7);
    agbase[i] = (long)(m0 + r) * EMB + cg * 8;
    bgbase[i] = (long)(n0t + r) * EMB + cg * 8;
    ldsoff[i] = (w * 32 + i * 8) * 64;
  }

  const int wm = w >> 1, wn = w & 1;
  const int q = lane >> 4, ln = lane & 15;
  int aoff[4][2], boff[4][2];
  #pragma unroll
  for (int t = 0; t < 4; t++) {
    int ra = wm * 64 + t * 16 + ln;
    int rb = wn * 64 + t * 16 + ln;
    #pragma unroll
    for (int ks = 0; ks < 2; ks++) {
      int c = ks * 4 + q;
      aoff[t][ks] = ra * 64 + ((c ^ (ra & 7)) * 8);
      boff[t][ks] = rb * 64 + ((c ^ (rb & 7)) * 8);
    }
  }

  f32x4 acc[4][4];
  #pragma unroll
  for (int i = 0; i < 4; i++)
    #pragma unroll
    for (int j = 0; j < 4; j++) acc[i][j] = (f32x4)0.f;

  for (int kb = 0; kb < EMB; kb += 64) {
    #pragma unroll
    for (int i = 0; i < 4; i++) {
      async_copy16(&As[ldsoff[i]], A  + agbase[i] + kb);
      async_copy16(&Bs[ldsoff[i]], Bt + bgbase[i] + kb);
    }
    __syncthreads();
    #pragma unroll
    for (int ks = 0; ks < 2; ks++) {
      bf16x8 af[4], bfr[4];
      #pragma unroll
      for (int t = 0; t < 4; t++) af[t]  = *(const bf16x8*)&As[aoff[t][ks]];
      #pragma unroll
      for (int t = 0; t < 4; t++) bfr[t] = *(const bf16x8*)&Bs[boff[t][ks]];
      #pragma unroll
      for (int mt = 0; mt < 4; mt++)
        #pragma unroll
        for (int nt = 0; nt < 4; nt++)
          acc[mt][nt] = __builtin_amdgcn_mfma_f32_16x16x32_bf16(af[mt], bfr[nt], acc[mt][nt], 0, 0, 0);
    }
    __syncthreads();
  }

  #pragma unroll
  for (int nt = 0; nt < 4; nt++) {
    int c = n0t + wn * 64 + nt * 16 + ln;
    float bv = bias[c];
    #pragma unroll
    for (int mt = 0; mt < 4; mt++) {
      int mrow = m0 + wm * 64 + mt * 16 + q * 4;
      #pragma unroll
      for (int v = 0; v < 4; v++)
        S[(long)(mrow + v) * FEAT + c] = acc[mt][nt][v] + bv;
    }
  }
}

// ---------- conv GEMM: 256x256 tile, BK=64, 8 waves, 8-phase counted-vmcnt ----------
// LDS 128 KiB = 2 dbuf x {A_ks0, A_ks1, B_ks0, B_ks1} x 8192 elems (16 KiB each).
// Region layout: pair p = row>>1 holds 8 slots of 16B; chunk c (8 elems) of row r
// stored at slot ((r&1)<<2 | c) ^ ((r>>1)&7)  -> uniform bank use for ds_read_b128,
// and global source is pre-swizzled so global_load_lds writes linearly (G21).
// Phase schedule per K-tile t (quadrant = (mh, ks)):
//   ph1 (mh0,ks0): read A(mh0)ks0 + B ks0; stage (t+1):A_ks1 -> buf^1
//   ph2 (mh1,ks0): read A(mh1)ks0;         stage (t+2):B_ks0 -> buf   (dead after ph1)
//   ph3 (mh0,ks1): read A(mh0)ks1 + B ks1; stage (t+2):A_ks0 -> buf   (dead after ph2)
//   ph4 (mh1,ks1): read A(mh1)ks1;         stage (t+2):B_ks1 -> buf   (dead after ph3)
//   end of ph4: s_waitcnt vmcnt(6)  (leaves exactly the 3 t+2 halves in flight,
//   guarantees tile t+1 fully landed). Never vmcnt(0) in steady state (T4).

#define MM4(MH, I, AV)                                                                               \
  acc[(MH)*4+(I)][0] = __builtin_amdgcn_mfma_f32_16x16x32_bf16(AV, b0_, acc[(MH)*4+(I)][0], 0, 0, 0); \
  acc[(MH)*4+(I)][1] = __builtin_amdgcn_mfma_f32_16x16x32_bf16(AV, b1_, acc[(MH)*4+(I)][1], 0, 0, 0); \
  acc[(MH)*4+(I)][2] = __builtin_amdgcn_mfma_f32_16x16x32_bf16(AV, b2_, acc[(MH)*4+(I)][2], 0, 0, 0); \
  acc[(MH)*4+(I)][3] = __builtin_amdgcn_mfma_f32_16x16x32_bf16(AV, b3_, acc[(MH)*4+(I)][3], 0, 0, 0);

#define ARD(MH, AB)                                                  \
    bf16x8 a0_ = *(const bf16x8*)&smem[(AB) + aoff[MH][0]];          \
    bf16x8 a1_ = *(const bf16x8*)&smem[(AB) + aoff[MH][1]];          \
    bf16x8 a2_ = *(const bf16x8*)&smem[(AB) + aoff[MH][2]];          \
    bf16x8 a3_ = *(const bf16x8*)&smem[(AB) + aoff[MH][3]];

#define BRD(BB)                                                      \
    b0_ = *(const bf16x8*)&smem[(BB) + boff[0]];                     \
    b1_ = *(const bf16x8*)&smem[(BB) + boff[1]];                     \
    b2_ = *(const bf16x8*)&smem[(BB) + boff[2]];                     \
    b3_ = *(const bf16x8*)&smem[(BB) + boff[3]];

#define PH_SYNC()                                                    \
    __builtin_amdgcn_s_barrier();                                    \
    asm volatile("s_waitcnt lgkmcnt(0)" ::: "memory");               \
    __builtin_amdgcn_sched_barrier(0);                               \
    __builtin_amdgcn_s_setprio(1)

#define PH_END()                                                     \
    __builtin_amdgcn_s_setprio(0);                                   \
    __builtin_amdgcn_s_barrier()

__global__ __launch_bounds__(512, 2)
void gemm8(const bf16_t* __restrict__ Axp, const bf16_t* __restrict__ Bt,
           const float* __restrict__ bias1, const float* __restrict__ bias2,
           const float* __restrict__ bias3, bf16_t* __restrict__ P, int Mtot) {
  __shared__ bf16_t smem[65536];   // 128 KiB

  const int tid  = threadIdx.x;
  const int lane = tid & 63, w = tid >> 6;
  const int wm = w >> 2, wn = w & 3;           // 2 x 4 wave grid, wave tile 128x64
  const int ln = lane & 15, q = lane >> 4;
  const int wbase = w * 512;                   // wave-uniform LDS base (elems) per stage call

  // T1: bijective XCD-chunked swizzle, then A-panel-major (6 consecutive ids share bx)
  const int nx   = gridDim.x;
  const int nwg  = nx * 6;                     // nwg % 8 == 0 (320*6 or 80*6)
  const int orig = blockIdx.y * nx + blockIdx.x;
  const int wgid = (orig & 7) * (nwg >> 3) + (orig >> 3);
  const int bx = wgid / 6, by = wgid % 6;
  const int m0  = bx * 256;
  const int n0t = by * 256;                    // Bt row base
  const int g   = by >> 1;                     // conv group
  const int NT  = 12 * (g + 1);                // K-tiles of 64 (Keff = 768*(g+1))

  // staging sources (pre-swizzled global addresses; LDS dest stays linear)
  long aSrc0, aSrc1, bSrc0, bSrc1;
  {
    int pair = (tid >> 3);
    int u    = (tid & 7) ^ (pair & 7);
    int row  = pair * 2 + (u >> 2);
    int c    = u & 3;
    int m    = m0 + row;
    aSrc0 = ((long)(m / SEQ) * SEQP + (m % SEQ)) * EMB + c * 8;
    bSrc0 = (long)(n0t + row) * KA + c * 8;
    pair += 64;
    u   = (tid & 7) ^ (pair & 7);
    row = pair * 2 + (u >> 2);
    c   = u & 3;
    m   = m0 + row;
    aSrc1 = ((long)(m / SEQ) * SEQP + (m % SEQ)) * EMB + c * 8;
    bSrc1 = (long)(n0t + row) * KA + c * 8;
  }

  auto stA = [&](int buf, int ks, int kb) {
    const int rb = buf * 32768 + ks * 8192;
    async_copy16(&smem[rb + wbase],        Axp + aSrc0 + kb + ks * 32);
    async_copy16(&smem[rb + 4096 + wbase], Axp + aSrc1 + kb + ks * 32);
  };
  auto stB = [&](int buf, int ks, int kb) {
    const int rb = buf * 32768 + 16384 + ks * 8192;
    async_copy16(&smem[rb + wbase],        Bt + bSrc0 + kb + ks * 32);
    async_copy16(&smem[rb + 4096 + wbase], Bt + bSrc1 + kb + ks * 32);
  };

  // fragment read offsets (elements within a region), swizzle-matched to staging
  int aoff[2][4], boff[4];
  #pragma unroll
  for (int mh = 0; mh < 2; mh++)
    #pragma unroll
    for (int t4 = 0; t4 < 4; t4++) {
      int r = wm * 128 + mh * 64 + t4 * 16 + ln;
      int slot = (q | ((r & 1) << 2)) ^ ((r >> 1) & 7);
      aoff[mh][t4] = (r >> 1) * 64 + slot * 8;
    }
  #pragma unroll
  for (int nf = 0; nf < 4; nf++) {
    int r = wn * 64 + nf * 16 + ln;
    int slot = (q | ((r & 1) << 2)) ^ ((r >> 1) & 7);
    boff[nf] = (r >> 1) * 64 + slot * 8;
  }

  f32x4 acc[8][4];
  #pragma unroll
  for (int i = 0; i < 8; i++)
    #pragma unroll
    for (int j = 0; j < 4; j++) acc[i][j] = (f32x4)0.f;

  // prologue: tile0 complete + tile1 {B_ks0, A_ks0, B_ks1} in flight (6 loads)
  stA(0, 0, 0);
  stA(0, 1, 0);
  stB(0, 0, 0);
  stB(0, 1, 0);
  stB(1, 0, 64);
  stA(1, 0, 64);
  stB(1, 1, 64);
  asm volatile("s_waitcnt vmcnt(6)" ::: "memory");
  __builtin_amdgcn_s_barrier();

  for (int t = 0; t < NT; ++t) {
    const int cb  = (t & 1) << 15;           // dbuf base (elems)
    const int ab0 = cb, ab1 = cb + 8192;
    const int bb0 = cb + 16384, bb1 = cb + 24576;
    const int nb  = (t & 1) ^ 1;
    bf16x8 b0_, b1_, b2_, b3_;

    { // phase 1: (mh0, ks0)
      ARD(0, ab0)
      BRD(bb0)
      if (t + 1 < NT) stA(nb, 1, (t + 1) * 64);
      PH_SYNC();
      MM4(0, 0, a0_) MM4(0, 1, a1_) MM4(0, 2, a2_) MM4(0, 3, a3_)
      PH_END();
    }
    { // phase 2: (mh1, ks0)
      ARD(1, ab0)
      if (t + 2 < NT) stB(t & 1, 0, (t + 2) * 64);
      PH_SYNC();
      MM4(1, 0, a0_) MM4(1, 1, a1_) MM4(1, 2, a2_) MM4(1, 3, a3_)
      PH_END();
    }
    { // phase 3: (mh0, ks1)
      ARD(0, ab1)
      BRD(bb1)
      if (t + 2 < NT) stA(t & 1, 0, (t + 2) * 64);
      PH_SYNC();
      MM4(0, 0, a0_) MM4(0, 1, a1_) MM4(0, 2, a2_) MM4(0, 3, a3_)
      PH_END();
    }
    { // phase 4: (mh1, ks1) + tile-boundary counted wait
      ARD(1, ab1)
      if (t + 2 < NT) stB(t & 1, 1, (t + 2) * 64);
      PH_SYNC();
      MM4(1, 0, a0_) MM4(1, 1, a1_) MM4(1, 2, a2_) MM4(1, 3, a3_)
      __builtin_amdgcn_s_setprio(0);
      if (t + 2 < NT)      { asm volatile("s_waitcnt vmcnt(6)" ::: "memory"); }
      else if (t + 1 < NT) { asm volatile("s_waitcnt vmcnt(0)" ::: "memory"); }
      __builtin_amdgcn_s_barrier();
    }
  }

  // epilogue: D row = q*4+v, col = ln per 16x16 frag; +bias, ReLU, short-conv zeroing
  const float* bias = (g == 0) ? bias1 : ((g == 1) ? bias2 : bias3);
  const int gc0 = (by & 1) * 256;
  #pragma unroll
  for (int nf = 0; nf < 4; nf++) {
    int c = gc0 + wn * 64 + nf * 16 + ln;
    float bv = bias[c];
    #pragma unroll
    for (int mf = 0; mf < 8; mf++) {
      int mrow = m0 + wm * 128 + mf * 16 + q * 4;
      #pragma unroll
      for (int v = 0; v < 4; v++) {
        int m = mrow + v;
        int l = m % SEQ;
        float val = acc[mf][nf][v] + bv;
        val = val > 0.f ? val : 0.f;
        if (l >= SEQ - g) val = 0.f;
        P[((long)g * Mtot + m) * FEAT + c] = (bf16_t)val;
      }
    }
  }
}

// ---------- epilogue: one block per batch element (chunk-local) ----------
__global__ __launch_bounds__(256)
void epilogue_k(const bf16_t* __restrict__ P, float* __restrict__ out, int b0, int Mtot) {
  const int bl = blockIdx.x;           // chunk-local batch index
  const long b = b0 + bl;              // global batch index
  const int t = threadIdx.x;
  const int lane = t & 63, w = t >> 6;
  const int c0 = t * 2;

  float code[SEQ][2];
  #pragma unroll
  for (int l = 0; l < SEQ; l++) { code[l][0] = 0.f; code[l][1] = 0.f; }
  float mg[3][2];

  #pragma unroll
  for (int gg = 0; gg < 3; gg++) {
    float mx0 = 0.f, mx1 = 0.f;
    #pragma unroll
    for (int l = 0; l < SEQ; l++) {
      uint32_t u = *(const uint32_t*)&P[((long)gg * Mtot + (long)bl * SEQ + l) * FEAT + c0];
      float v0 = __builtin_bit_cast(float, u << 16);
      float v1 = __builtin_bit_cast(float, u & 0xffff0000u);
      code[l][0] = fmaxf(code[l][0], v0);
      code[l][1] = fmaxf(code[l][1], v1);
      mx0 = fmaxf(mx0, v0); mx1 = fmaxf(mx1, v1);
    }
    mg[gg][0] = mx0; mg[gg][1] = mx1;
  }

  __shared__ float red[SEQ][4];
  __shared__ float redp[4];

  #pragma unroll
  for (int l = 0; l < SEQ; l++) {
    float s = code[l][0] * code[l][0] + code[l][1] * code[l][1];
    #pragma unroll
    for (int off = 32; off; off >>= 1) s += __shfl_xor(s, off, 64);
    if (lane == 0) red[l][w] = s;
  }
  float p0 = (mg[0][0] + mg[1][0] + mg[2][0]) * (1.f / 3.f);
  float p1 = (mg[0][1] + mg[1][1] + mg[2][1]) * (1.f / 3.f);
  float sp = p0 * p0 + p1 * p1;
  #pragma unroll
  for (int off = 32; off; off >>= 1) sp += __shfl_xor(sp, off, 64);
  if (lane == 0) redp[w] = sp;
  __syncthreads();

  float rnorm[SEQ];
  #pragma unroll
  for (int l = 0; l < SEQ; l++) {
    float s = red[l][0] + red[l][1] + red[l][2] + red[l][3];
    rnorm[l] = 1.f / fmaxf(sqrtf(s), 1e-12f);
  }
  float sP = redp[0] + redp[1] + redp[2] + redp[3];
  float rnp = 1.f / fmaxf(sqrtf(sP), 1e-12f);

  // words_out [b][c][l]
  #pragma unroll
  for (int cc = 0; cc < 2; cc++) {
    long base = b * (FEAT * SEQ) + (long)(c0 + cc) * SEQ;
    #pragma unroll
    for (int l0 = 0; l0 < SEQ; l0 += 4) {
      float4 v;
      v.x = code[l0 + 0][cc] * rnorm[l0 + 0];
      v.y = code[l0 + 1][cc] * rnorm[l0 + 1];
      v.z = code[l0 + 2][cc] * rnorm[l0 + 2];
      v.w = code[l0 + 3][cc] * rnorm[l0 + 3];
      *(float4*)&out[base + l0] = v;
    }
  }
  // word_vector [b][c]
  out[WV_BASE + b * FEAT + c0]     = p0 * rnp;
  out[WV_BASE + b * FEAT + c0 + 1] = p1 * rnp;
}

// ---------- launch ----------
extern "C" void kernel_launch(void* const* d_in, const int* in_sizes, int n_in,
                              void* d_out, int out_size, void* d_ws, size_t ws_size,
                              hipStream_t stream) {
  const float* words = (const float*)d_in[0];
  const float* sent  = (const float*)d_in[1];
  const float* W1 = (const float*)d_in[2];
  const float* b1 = (const float*)d_in[3];
  const float* W2 = (const float*)d_in[4];
  const float* b2 = (const float*)d_in[5];
  const float* W3 = (const float*)d_in[6];
  const float* b3 = (const float*)d_in[7];
  const float* Wp = (const float*)d_in[8];
  const float* bp = (const float*)d_in[9];
  float* out = (float*)d_out;
  char* ws = (char*)d_ws;

  int CBr, NCH;
  if (ws_size >= (size_t)WS_FULL)     { CBr = 4096; NCH = 1; }   // unchunked
  else if (ws_size >= (size_t)WS_MIN) { CBr = 1024; NCH = 4; }   // fallback: 4 chunks
  else return;   // refuse to scribble OOB

  const int Mtot = CBr * SEQ;
  bf16_t* Bt    = (bf16_t*)(ws + BT_OFF);
  bf16_t* Wpt   = (bf16_t*)(ws + WPT_OFF);
  bf16_t* sentX = (bf16_t*)(ws + SENTX_OFF);
  bf16_t* Xpad  = (bf16_t*)(ws + XPAD_OFF);
  bf16_t* P     = (bf16_t*)(ws + XPAD_OFF + (long)CBr * SEQP * EMB * 2);

  // weights + sentence path (once)
  pack_bt<<<13824, 256, 0, stream>>>(W1, W2, W3, Bt);    // 1536*2304/256
  pack_wpt<<<1536, 256, 0, stream>>>(Wp, Wpt);           // 512*768/256
  pack_sent<<<3072, 256, 0, stream>>>(sent, sentX);      // 4096*768/4/256
  gemm_sent<<<dim3(32, 4), 256, 0, stream>>>(sentX, Wpt, bp, out + SENT_BASE);

  // conv path
  for (int ch = 0; ch < NCH; ch++) {
    int b0 = ch * CBr;
    pack_xpad<<<(CBr * SEQP * EMB) / 1024, 256, 0, stream>>>(words + (long)b0 * SEQ * EMB, Xpad);
    gemm8<<<dim3(Mtot / 256, 6), 512, 0, stream>>>(Xpad, Bt, b1, b2, b3, P, Mtot);
    epilogue_k<<<CBr, 256, 0, stream>>>(P, out, b0, Mtot);
  }
}

// Round 3
// 919.100 us; speedup vs baseline: 1.0580x; 1.0151x over previous
//
#include <hip/hip_runtime.h>
#include <hip/hip_bf16.h>
#include <stdint.h>

typedef __bf16 bf16_t;
typedef __bf16 bf16x8 __attribute__((ext_vector_type(8)));
typedef float f32x4 __attribute__((ext_vector_type(4)));

// ---------- constants ----------
#define BS       4096
#define SEQ      20
#define SEQP     22          // padded rows per batch elem (2 zero rows)
#define EMB      768
#define FEAT     512
#define KA       2304        // 3*768 virtual K
// d_out layout (floats)
#define WV_BASE   (41943040L)   // 4096*512*20
#define SENT_BASE (44040192L)

// ws layout (bytes). P offset depends on runtime chunk size CB:
//   P_OFF = XPAD_OFF + CB*22*768*2
#define BT_OFF    0L                        // 1536*2304*2 = 7077888
#define WPT_OFF   7077888L                  // 512*768*2   = 786432
#define SENTX_OFF 7864320L                  // 4096*768*2  = 6291456
#define XPAD_OFF  14155776L
#define WS_MIN    111673344L                // CB=1024 (4-chunk) total
#define WS_FULL   404226048L                // CB=4096 (unchunked) total

__device__ __forceinline__ void async_copy16(void* lds, const void* g) {
  __builtin_amdgcn_global_load_lds(
      (__attribute__((address_space(1))) void*)(void*)g,
      (__attribute__((address_space(3))) void*)lds,
      16, 0, 0);
}

// ---------- pack kernels ----------
// one chunk of words [CB,20,768] fp32 -> Xpad [CB,22,768] bf16 (rows 20,21 zero)
__global__ void pack_xpad(const float* __restrict__ words, bf16_t* __restrict__ Xpad) {
  long idx4 = ((long)blockIdx.x * blockDim.x + threadIdx.x) * 4;   // < CB*22*768
  long row = idx4 / EMB;          // b_local*22 + r
  int  d   = (int)(idx4 % EMB);
  long b   = row / SEQP;
  int  r   = (int)(row % SEQP);
  ushort4 o;
  if (r < SEQ) {
    float4 v = *(const float4*)(words + ((b * SEQ + r) * EMB + d));
    o.x = __builtin_bit_cast(unsigned short, (bf16_t)v.x);
    o.y = __builtin_bit_cast(unsigned short, (bf16_t)v.y);
    o.z = __builtin_bit_cast(unsigned short, (bf16_t)v.z);
    o.w = __builtin_bit_cast(unsigned short, (bf16_t)v.w);
  } else {
    o.x = 0; o.y = 0; o.z = 0; o.w = 0;
  }
  *(ushort4*)(&Xpad[idx4]) = o;
}

__global__ void pack_sent(const float* __restrict__ sent, bf16_t* __restrict__ Xs) {
  long idx4 = ((long)blockIdx.x * blockDim.x + threadIdx.x) * 4;   // < 4096*768
  float4 v = *(const float4*)(sent + idx4);
  ushort4 o;
  o.x = __builtin_bit_cast(unsigned short, (bf16_t)v.x);
  o.y = __builtin_bit_cast(unsigned short, (bf16_t)v.y);
  o.z = __builtin_bit_cast(unsigned short, (bf16_t)v.z);
  o.w = __builtin_bit_cast(unsigned short, (bf16_t)v.w);
  *(ushort4*)(&Xs[idx4]) = o;
}

// Bt[n][k], n in [0,1536), k in [0,2304): group g=n>>9, c=n&511, j=k/768, d=k%768
__global__ void pack_bt(const float* __restrict__ W1, const float* __restrict__ W2,
                        const float* __restrict__ W3, bf16_t* __restrict__ Bt) {
  long idx = (long)blockIdx.x * blockDim.x + threadIdx.x;          // < 1536*2304
  int n = (int)(idx / KA), k = (int)(idx % KA);
  int g = n >> 9, c = n & 511;
  int j = k / EMB, d = k % EMB;
  float v = 0.f;
  if (j <= g) {
    const float* W = (g == 0) ? W1 : ((g == 1) ? W2 : W3);
    v = W[((long)j * EMB + d) * FEAT + c];
  }
  Bt[idx] = (bf16_t)v;
}

// Wpt[n][k] = Wp[k][n]
__global__ void pack_wpt(const float* __restrict__ Wp, bf16_t* __restrict__ Wpt) {
  long idx = (long)blockIdx.x * blockDim.x + threadIdx.x;          // < 512*768
  int n = (int)(idx / EMB), k = (int)(idx % EMB);
  Wpt[idx] = (bf16_t)Wp[(long)k * FEAT + n];
}

// ---------- sentence GEMM (proven 128^2 2-barrier kernel, K=768, small) ----------
__global__ __launch_bounds__(256, 2)
void gemm_sent(const bf16_t* __restrict__ A, const bf16_t* __restrict__ Bt,
               const float* __restrict__ bias, float* __restrict__ S) {
  __shared__ bf16_t As[128 * 64];
  __shared__ bf16_t Bs[128 * 64];

  const int tid  = threadIdx.x;
  const int lane = tid & 63;
  const int w    = tid >> 6;
  const int m0   = blockIdx.x * 128;
  const int n0t  = blockIdx.y * 128;

  long agbase[4], bgbase[4];
  int  ldsoff[4];
  #pragma unroll
  for (int i = 0; i < 4; i++) {
    int r = w * 32 + i * 8 + (lane >> 3);
    int cg = (lane & 7) ^ (r & 7);
    agbase[i] = (long)(m0 + r) * EMB + cg * 8;
    bgbase[i] = (long)(n0t + r) * EMB + cg * 8;
    ldsoff[i] = (w * 32 + i * 8) * 64;
  }

  const int wm = w >> 1, wn = w & 1;
  const int q = lane >> 4, ln = lane & 15;
  int aoff[4][2], boff[4][2];
  #pragma unroll
  for (int t = 0; t < 4; t++) {
    int ra = wm * 64 + t * 16 + ln;
    int rb = wn * 64 + t * 16 + ln;
    #pragma unroll
    for (int ks = 0; ks < 2; ks++) {
      int c = ks * 4 + q;
      aoff[t][ks] = ra * 64 + ((c ^ (ra & 7)) * 8);
      boff[t][ks] = rb * 64 + ((c ^ (rb & 7)) * 8);
    }
  }

  f32x4 acc[4][4];
  #pragma unroll
  for (int i = 0; i < 4; i++)
    #pragma unroll
    for (int j = 0; j < 4; j++) acc[i][j] = (f32x4)0.f;

  for (int kb = 0; kb < EMB; kb += 64) {
    #pragma unroll
    for (int i = 0; i < 4; i++) {
      async_copy16(&As[ldsoff[i]], A  + agbase[i] + kb);
      async_copy16(&Bs[ldsoff[i]], Bt + bgbase[i] + kb);
    }
    __syncthreads();
    #pragma unroll
    for (int ks = 0; ks < 2; ks++) {
      bf16x8 af[4], bfr[4];
      #pragma unroll
      for (int t = 0; t < 4; t++) af[t]  = *(const bf16x8*)&As[aoff[t][ks]];
      #pragma unroll
      for (int t = 0; t < 4; t++) bfr[t] = *(const bf16x8*)&Bs[boff[t][ks]];
      #pragma unroll
      for (int mt = 0; mt < 4; mt++)
        #pragma unroll
        for (int nt = 0; nt < 4; nt++)
          acc[mt][nt] = __builtin_amdgcn_mfma_f32_16x16x32_bf16(af[mt], bfr[nt], acc[mt][nt], 0, 0, 0);
    }
    __syncthreads();
  }

  #pragma unroll
  for (int nt = 0; nt < 4; nt++) {
    int c = n0t + wn * 64 + nt * 16 + ln;
    float bv = bias[c];
    #pragma unroll
    for (int mt = 0; mt < 4; mt++) {
      int mrow = m0 + wm * 64 + mt * 16 + q * 4;
      #pragma unroll
      for (int v = 0; v < 4; v++)
        S[(long)(mrow + v) * FEAT + c] = acc[mt][nt][v] + bv;
    }
  }
}

// ---------- conv GEMM: 256x256 tile, BK=64, 8 waves ----------
// Pipelined-fragment 4-phase schedule, ONE barrier per phase:
//   each phase issues the NEXT phase's ds_reads (ping-pong frag regs) before its
//   own 16-MFMA cluster (sched_barrier(0) pins the order). The waitcnt pass then
//   emits COUNTED lgkmcnt (drain current frags, leave next in flight), so the
//   LDS-read window of phase p+1 overlaps the MFMA window of phase p.
// Region recycle safety (1 barrier/phase): every region's last reader is DRAINED
//   (counted lgkm before its MFMA) before that phase's exit barrier, and the
//   overwriting stage is issued after that barrier:
//     ph2 stages B_ks0(buf) [t+2]  — last reader bP drained pre-MFMA1
//     ph3 stages A_ks0(buf) [t+2]  — last readers aP(top)/aN(ph1) drained pre-MFMA1/2
//     ph4 stages B_ks1(buf) [t+2]  — last reader bN drained pre-MFMA3
//     ph1 stages A_ks1(buf^1)[t+1] — last readers were tile t-1's ph2/ph3 reads
// Tile boundary: vmcnt(4) before ph4's exit barrier. Outstanding then = 4 newest
//   = ph3/ph4's t+2 halves; draining past them completes ALL of tile t+1
//   (B_ks0 from t-1.ph2, A_ks0 from t-1.ph3, B_ks1 from t-1.ph4, A_ks1 from t.ph1).
//   t==NT-2 has no t+2 stages -> all outstanding are t+1 pieces -> vmcnt(0).

#define MFMA16(BASE, A0, A1, A2, A3, B0, B1, B2, B3)                                        \
  acc[(BASE)+0][0] = __builtin_amdgcn_mfma_f32_16x16x32_bf16(A0, B0, acc[(BASE)+0][0], 0, 0, 0); \
  acc[(BASE)+0][1] = __builtin_amdgcn_mfma_f32_16x16x32_bf16(A0, B1, acc[(BASE)+0][1], 0, 0, 0); \
  acc[(BASE)+0][2] = __builtin_amdgcn_mfma_f32_16x16x32_bf16(A0, B2, acc[(BASE)+0][2], 0, 0, 0); \
  acc[(BASE)+0][3] = __builtin_amdgcn_mfma_f32_16x16x32_bf16(A0, B3, acc[(BASE)+0][3], 0, 0, 0); \
  acc[(BASE)+1][0] = __builtin_amdgcn_mfma_f32_16x16x32_bf16(A1, B0, acc[(BASE)+1][0], 0, 0, 0); \
  acc[(BASE)+1][1] = __builtin_amdgcn_mfma_f32_16x16x32_bf16(A1, B1, acc[(BASE)+1][1], 0, 0, 0); \
  acc[(BASE)+1][2] = __builtin_amdgcn_mfma_f32_16x16x32_bf16(A1, B2, acc[(BASE)+1][2], 0, 0, 0); \
  acc[(BASE)+1][3] = __builtin_amdgcn_mfma_f32_16x16x32_bf16(A1, B3, acc[(BASE)+1][3], 0, 0, 0); \
  acc[(BASE)+2][0] = __builtin_amdgcn_mfma_f32_16x16x32_bf16(A2, B0, acc[(BASE)+2][0], 0, 0, 0); \
  acc[(BASE)+2][1] = __builtin_amdgcn_mfma_f32_16x16x32_bf16(A2, B1, acc[(BASE)+2][1], 0, 0, 0); \
  acc[(BASE)+2][2] = __builtin_amdgcn_mfma_f32_16x16x32_bf16(A2, B2, acc[(BASE)+2][2], 0, 0, 0); \
  acc[(BASE)+2][3] = __builtin_amdgcn_mfma_f32_16x16x32_bf16(A2, B3, acc[(BASE)+2][3], 0, 0, 0); \
  acc[(BASE)+3][0] = __builtin_amdgcn_mfma_f32_16x16x32_bf16(A3, B0, acc[(BASE)+3][0], 0, 0, 0); \
  acc[(BASE)+3][1] = __builtin_amdgcn_mfma_f32_16x16x32_bf16(A3, B1, acc[(BASE)+3][1], 0, 0, 0); \
  acc[(BASE)+3][2] = __builtin_amdgcn_mfma_f32_16x16x32_bf16(A3, B2, acc[(BASE)+3][2], 0, 0, 0); \
  acc[(BASE)+3][3] = __builtin_amdgcn_mfma_f32_16x16x32_bf16(A3, B3, acc[(BASE)+3][3], 0, 0, 0);

__global__ __launch_bounds__(512, 2)
void gemm8(const bf16_t* __restrict__ Axp, const bf16_t* __restrict__ Bt,
           const float* __restrict__ bias1, const float* __restrict__ bias2,
           const float* __restrict__ bias3, bf16_t* __restrict__ P, int Mtot) {
  __shared__ bf16_t smem[65536];   // 128 KiB

  const int tid  = threadIdx.x;
  const int lane = tid & 63, w = tid >> 6;
  const int wm = w >> 2, wn = w & 3;           // 2 x 4 wave grid, wave tile 128x64
  const int ln = lane & 15, q = lane >> 4;
  const int wbase = w * 512;                   // wave-uniform LDS base (elems) per stage call

  // T1: bijective XCD-chunked swizzle, then A-panel-major (6 consecutive ids share bx)
  const int nx   = gridDim.x;
  const int nwg  = nx * 6;                     // nwg % 8 == 0 (320*6 or 80*6)
  const int orig = blockIdx.y * nx + blockIdx.x;
  const int wgid = (orig & 7) * (nwg >> 3) + (orig >> 3);
  const int bx = wgid / 6, by = wgid % 6;
  const int m0  = bx * 256;
  const int n0t = by * 256;                    // Bt row base
  const int g   = by >> 1;                     // conv group
  const int NT  = 12 * (g + 1);                // K-tiles of 64 (Keff = 768*(g+1))

  // staging sources (pre-swizzled global addresses; LDS dest stays linear)
  long aSrc0, aSrc1, bSrc0, bSrc1;
  {
    int pair = (tid >> 3);
    int u    = (tid & 7) ^ (pair & 7);
    int row  = pair * 2 + (u >> 2);
    int c    = u & 3;
    int m    = m0 + row;
    aSrc0 = ((long)(m / SEQ) * SEQP + (m % SEQ)) * EMB + c * 8;
    bSrc0 = (long)(n0t + row) * KA + c * 8;
    pair += 64;
    u   = (tid & 7) ^ (pair & 7);
    row = pair * 2 + (u >> 2);
    c   = u & 3;
    m   = m0 + row;
    aSrc1 = ((long)(m / SEQ) * SEQP + (m % SEQ)) * EMB + c * 8;
    bSrc1 = (long)(n0t + row) * KA + c * 8;
  }

  auto stA = [&](int buf, int ks, int kb) {
    const int rb = buf * 32768 + ks * 8192;
    async_copy16(&smem[rb + wbase],        Axp + aSrc0 + kb + ks * 32);
    async_copy16(&smem[rb + 4096 + wbase], Axp + aSrc1 + kb + ks * 32);
  };
  auto stB = [&](int buf, int ks, int kb) {
    const int rb = buf * 32768 + 16384 + ks * 8192;
    async_copy16(&smem[rb + wbase],        Bt + bSrc0 + kb + ks * 32);
    async_copy16(&smem[rb + 4096 + wbase], Bt + bSrc1 + kb + ks * 32);
  };

  // fragment read offsets (elements within a region), swizzle-matched to staging
  int aoff[2][4], boff[4];
  #pragma unroll
  for (int mh = 0; mh < 2; mh++)
    #pragma unroll
    for (int t4 = 0; t4 < 4; t4++) {
      int r = wm * 128 + mh * 64 + t4 * 16 + ln;
      int slot = (q | ((r & 1) << 2)) ^ ((r >> 1) & 7);
      aoff[mh][t4] = (r >> 1) * 64 + slot * 8;
    }
  #pragma unroll
  for (int nf = 0; nf < 4; nf++) {
    int r = wn * 64 + nf * 16 + ln;
    int slot = (q | ((r & 1) << 2)) ^ ((r >> 1) & 7);
    boff[nf] = (r >> 1) * 64 + slot * 8;
  }

  f32x4 acc[8][4];
  #pragma unroll
  for (int i = 0; i < 8; i++)
    #pragma unroll
    for (int j = 0; j < 4; j++) acc[i][j] = (f32x4)0.f;

  // prologue: tile0 complete + tile1 {B_ks0, A_ks0, B_ks1} in flight (6 loads)
  stA(0, 0, 0);
  stA(0, 1, 0);
  stB(0, 0, 0);
  stB(0, 1, 0);
  stB(1, 0, 64);
  stA(1, 0, 64);
  stB(1, 1, 64);
  asm volatile("s_waitcnt vmcnt(6)" ::: "memory");   // 14 issued; drain tile0's 8
  __builtin_amdgcn_s_barrier();

  for (int t = 0; t < NT; ++t) {
    const int cb  = (t & 1) << 15;           // dbuf base (elems)
    const int ab0 = cb, ab1 = cb + 8192;
    const int bb0 = cb + 16384, bb1 = cb + 24576;
    const int nb  = (t & 1) ^ 1;

    // tile-top reads: ph1 frags (A mh0 ks0, B ks0) — tile t guaranteed staged
    bf16x8 aP0 = *(const bf16x8*)&smem[ab0 + aoff[0][0]];
    bf16x8 aP1 = *(const bf16x8*)&smem[ab0 + aoff[0][1]];
    bf16x8 aP2 = *(const bf16x8*)&smem[ab0 + aoff[0][2]];
    bf16x8 aP3 = *(const bf16x8*)&smem[ab0 + aoff[0][3]];
    bf16x8 bP0 = *(const bf16x8*)&smem[bb0 + boff[0]];
    bf16x8 bP1 = *(const bf16x8*)&smem[bb0 + boff[1]];
    bf16x8 bP2 = *(const bf16x8*)&smem[bb0 + boff[2]];
    bf16x8 bP3 = *(const bf16x8*)&smem[bb0 + boff[3]];

    { // phase 1: reads for ph2 (A mh1 ks0), stage t+1's A_ks1, MFMA (aP,bP)
      bf16x8 aN0 = *(const bf16x8*)&smem[ab0 + aoff[1][0]];
      bf16x8 aN1 = *(const bf16x8*)&smem[ab0 + aoff[1][1]];
      bf16x8 aN2 = *(const bf16x8*)&smem[ab0 + aoff[1][2]];
      bf16x8 aN3 = *(const bf16x8*)&smem[ab0 + aoff[1][3]];
      if (t + 1 < NT) stA(nb, 1, (t + 1) * 64);
      __builtin_amdgcn_sched_barrier(0);
      __builtin_amdgcn_s_setprio(1);
      MFMA16(0, aP0, aP1, aP2, aP3, bP0, bP1, bP2, bP3)
      __builtin_amdgcn_s_setprio(0);
      __builtin_amdgcn_s_barrier();

      // phase 2: reads for ph3 (A mh0 ks1, B ks1), stage t+2's B_ks0, MFMA (aN,bP)
      bf16x8 aQ0 = *(const bf16x8*)&smem[ab1 + aoff[0][0]];
      bf16x8 aQ1 = *(const bf16x8*)&smem[ab1 + aoff[0][1]];
      bf16x8 aQ2 = *(const bf16x8*)&smem[ab1 + aoff[0][2]];
      bf16x8 aQ3 = *(const bf16x8*)&smem[ab1 + aoff[0][3]];
      bf16x8 bN0 = *(const bf16x8*)&smem[bb1 + boff[0]];
      bf16x8 bN1 = *(const bf16x8*)&smem[bb1 + boff[1]];
      bf16x8 bN2 = *(const bf16x8*)&smem[bb1 + boff[2]];
      bf16x8 bN3 = *(const bf16x8*)&smem[bb1 + boff[3]];
      if (t + 2 < NT) stB(t & 1, 0, (t + 2) * 64);
      __builtin_amdgcn_sched_barrier(0);
      __builtin_amdgcn_s_setprio(1);
      MFMA16(4, aN0, aN1, aN2, aN3, bP0, bP1, bP2, bP3)
      __builtin_amdgcn_s_setprio(0);
      __builtin_amdgcn_s_barrier();

      // phase 3: reads for ph4 (A mh1 ks1), stage t+2's A_ks0, MFMA (aQ,bN)
      bf16x8 aR0 = *(const bf16x8*)&smem[ab1 + aoff[1][0]];
      bf16x8 aR1 = *(const bf16x8*)&smem[ab1 + aoff[1][1]];
      bf16x8 aR2 = *(const bf16x8*)&smem[ab1 + aoff[1][2]];
      bf16x8 aR3 = *(const bf16x8*)&smem[ab1 + aoff[1][3]];
      if (t + 2 < NT) stA(t & 1, 0, (t + 2) * 64);
      __builtin_amdgcn_sched_barrier(0);
      __builtin_amdgcn_s_setprio(1);
      MFMA16(0, aQ0, aQ1, aQ2, aQ3, bN0, bN1, bN2, bN3)
      __builtin_amdgcn_s_setprio(0);
      __builtin_amdgcn_s_barrier();

      // phase 4: stage t+2's B_ks1, MFMA (aR,bN), tile-boundary counted wait
      if (t + 2 < NT) stB(t & 1, 1, (t + 2) * 64);
      __builtin_amdgcn_sched_barrier(0);
      __builtin_amdgcn_s_setprio(1);
      MFMA16(4, aR0, aR1, aR2, aR3, bN0, bN1, bN2, bN3)
      __builtin_amdgcn_s_setprio(0);
      if (t + 2 < NT)      { asm volatile("s_waitcnt vmcnt(4)" ::: "memory"); }
      else if (t + 1 < NT) { asm volatile("s_waitcnt vmcnt(0)" ::: "memory"); }
      if (t + 1 < NT) __builtin_amdgcn_s_barrier();
    }
  }

  // epilogue: D row = q*4+v, col = ln per 16x16 frag; +bias, ReLU, short-conv zeroing
  const float* bias = (g == 0) ? bias1 : ((g == 1) ? bias2 : bias3);
  const int gc0 = (by & 1) * 256;
  #pragma unroll
  for (int nf = 0; nf < 4; nf++) {
    int c = gc0 + wn * 64 + nf * 16 + ln;
    float bv = bias[c];
    #pragma unroll
    for (int mf = 0; mf < 8; mf++) {
      int mrow = m0 + wm * 128 + mf * 16 + q * 4;
      #pragma unroll
      for (int v = 0; v < 4; v++) {
        int m = mrow + v;
        int l = m % SEQ;
        float val = acc[mf][nf][v] + bv;
        val = val > 0.f ? val : 0.f;
        if (l >= SEQ - g) val = 0.f;
        P[((long)g * Mtot + m) * FEAT + c] = (bf16_t)val;
      }
    }
  }
}

// ---------- epilogue: one block per batch element (chunk-local) ----------
__global__ __launch_bounds__(256)
void epilogue_k(const bf16_t* __restrict__ P, float* __restrict__ out, int b0, int Mtot) {
  const int bl = blockIdx.x;           // chunk-local batch index
  const long b = b0 + bl;              // global batch index
  const int t = threadIdx.x;
  const int lane = t & 63, w = t >> 6;
  const int c0 = t * 2;

  float code[SEQ][2];
  #pragma unroll
  for (int l = 0; l < SEQ; l++) { code[l][0] = 0.f; code[l][1] = 0.f; }
  float mg[3][2];

  #pragma unroll
  for (int gg = 0; gg < 3; gg++) {
    float mx0 = 0.f, mx1 = 0.f;
    #pragma unroll
    for (int l = 0; l < SEQ; l++) {
      uint32_t u = *(const uint32_t*)&P[((long)gg * Mtot + (long)bl * SEQ + l) * FEAT + c0];
      float v0 = __builtin_bit_cast(float, u << 16);
      float v1 = __builtin_bit_cast(float, u & 0xffff0000u);
      code[l][0] = fmaxf(code[l][0], v0);
      code[l][1] = fmaxf(code[l][1], v1);
      mx0 = fmaxf(mx0, v0); mx1 = fmaxf(mx1, v1);
    }
    mg[gg][0] = mx0; mg[gg][1] = mx1;
  }

  __shared__ float red[SEQ][4];
  __shared__ float redp[4];

  #pragma unroll
  for (int l = 0; l < SEQ; l++) {
    float s = code[l][0] * code[l][0] + code[l][1] * code[l][1];
    #pragma unroll
    for (int off = 32; off; off >>= 1) s += __shfl_xor(s, off, 64);
    if (lane == 0) red[l][w] = s;
  }
  float p0 = (mg[0][0] + mg[1][0] + mg[2][0]) * (1.f / 3.f);
  float p1 = (mg[0][1] + mg[1][1] + mg[2][1]) * (1.f / 3.f);
  float sp = p0 * p0 + p1 * p1;
  #pragma unroll
  for (int off = 32; off; off >>= 1) sp += __shfl_xor(sp, off, 64);
  if (lane == 0) redp[w] = sp;
  __syncthreads();

  float rnorm[SEQ];
  #pragma unroll
  for (int l = 0; l < SEQ; l++) {
    float s = red[l][0] + red[l][1] + red[l][2] + red[l][3];
    rnorm[l] = 1.f / fmaxf(sqrtf(s), 1e-12f);
  }
  float sP = redp[0] + redp[1] + redp[2] + redp[3];
  float rnp = 1.f / fmaxf(sqrtf(sP), 1e-12f);

  // words_out [b][c][l]
  #pragma unroll
  for (int cc = 0; cc < 2; cc++) {
    long base = b * (FEAT * SEQ) + (long)(c0 + cc) * SEQ;
    #pragma unroll
    for (int l0 = 0; l0 < SEQ; l0 += 4) {
      float4 v;
      v.x = code[l0 + 0][cc] * rnorm[l0 + 0];
      v.y = code[l0 + 1][cc] * rnorm[l0 + 1];
      v.z = code[l0 + 2][cc] * rnorm[l0 + 2];
      v.w = code[l0 + 3][cc] * rnorm[l0 + 3];
      *(float4*)&out[base + l0] = v;
    }
  }
  // word_vector [b][c]
  out[WV_BASE + b * FEAT + c0]     = p0 * rnp;
  out[WV_BASE + b * FEAT + c0 + 1] = p1 * rnp;
}

// ---------- launch ----------
extern "C" void kernel_launch(void* const* d_in, const int* in_sizes, int n_in,
                              void* d_out, int out_size, void* d_ws, size_t ws_size,
                              hipStream_t stream) {
  const float* words = (const float*)d_in[0];
  const float* sent  = (const float*)d_in[1];
  const float* W1 = (const float*)d_in[2];
  const float* b1 = (const float*)d_in[3];
  const float* W2 = (const float*)d_in[4];
  const float* b2 = (const float*)d_in[5];
  const float* W3 = (const float*)d_in[6];
  const float* b3 = (const float*)d_in[7];
  const float* Wp = (const float*)d_in[8];
  const float* bp = (const float*)d_in[9];
  float* out = (float*)d_out;
  char* ws = (char*)d_ws;

  int CBr, NCH;
  if (ws_size >= (size_t)WS_FULL)     { CBr = 4096; NCH = 1; }   // unchunked
  else if (ws_size >= (size_t)WS_MIN) { CBr = 1024; NCH = 4; }   // fallback: 4 chunks
  else return;   // refuse to scribble OOB

  const int Mtot = CBr * SEQ;
  bf16_t* Bt    = (bf16_t*)(ws + BT_OFF);
  bf16_t* Wpt   = (bf16_t*)(ws + WPT_OFF);
  bf16_t* sentX = (bf16_t*)(ws + SENTX_OFF);
  bf16_t* Xpad  = (bf16_t*)(ws + XPAD_OFF);
  bf16_t* P     = (bf16_t*)(ws + XPAD_OFF + (long)CBr * SEQP * EMB * 2);

  // weights + sentence path (once)
  pack_bt<<<13824, 256, 0, stream>>>(W1, W2, W3, Bt);    // 1536*2304/256
  pack_wpt<<<1536, 256, 0, stream>>>(Wp, Wpt);           // 512*768/256
  pack_sent<<<3072, 256, 0, stream>>>(sent, sentX);      // 4096*768/4/256
  gemm_sent<<<dim3(32, 4), 256, 0, stream>>>(sentX, Wpt, bp, out + SENT_BASE);

  // conv path
  for (int ch = 0; ch < NCH; ch++) {
    int b0 = ch * CBr;
    pack_xpad<<<(CBr * SEQP * EMB) / 1024, 256, 0, stream>>>(words + (long)b0 * SEQ * EMB, Xpad);
    gemm8<<<dim3(Mtot / 256, 6), 512, 0, stream>>>(Xpad, Bt, b1, b2, b3, P, Mtot);
    epilogue_k<<<CBr, 256, 0, stream>>>(P, out, b0, Mtot);
  }
}